// Round 9
// baseline (269.702 us; speedup 1.0000x reference)
//
#include <hip/hip_runtime.h>
#include <cstdint>
#include <cstddef>

#define NP  1024
#define FD  10
#define BSZ 128
#define TPB 64
#define RPT 16   // rows per lane: 64 lanes x 16 = 1024 rows per (pair,dir) block

// One block = one wave = one (pair, dir). bid = pair*2 + d.
//   d=0: rows = state(ag), cols = goal(dg)   (reward_s2g)
//   d=1: rows = goal(dg),  cols = state(ag)  (reward_g2s)
// Shift-reduced distance: argmin_m [rs + cs_m - 2 r.c_m] == argmin_m [cs_m + r.c2_m],
// c2 = -2*c staged in LDS. Main loop: 8 cols/iter, wave-uniform b128 broadcasts,
// explicit register double-buffer (load batch g+1 while computing batch g) so the
// lgkmcnt wait is covered by ~600 VALU instrs even at 1 wave/SIMD. Tracker keeps
// the winning 8-col block; exact first-tie index recovered by replaying the
// identical fmaf chain from GLOBAL (bit-identical to the staged values).
extern "C" __global__ __launch_bounds__(TPB)
void chamfer_pairs(const float* __restrict__ ag, const float* __restrict__ dg,
                   const float* __restrict__ nmean, const float* __restrict__ nstd,
                   float* __restrict__ out /* [BSZ], pre-zeroed */)
{
    __shared__ __align__(16) float4 cvis[NP];   // -2 * normalized col vis (16 KB)
    __shared__ __align__(16) float  csh[NP];    // ||col vis||^2            (4 KB)

    const int bid  = blockIdx.x;        // 0..1023
    const int pair = bid >> 1;
    const int d    = bid & 1;
    const int tid  = threadIdx.x;

    const float* rowsrc = ((d == 0) ? ag : dg) + (size_t)pair * (NP * FD);
    const float* colsrc = ((d == 0) ? dg : ag) + (size_t)pair * (NP * FD);

    // -2*(std, mean) for vis features 5..8 (uniform -> scalar regs).
    const float s5 = -2.0f * nstd[5], m5 = -2.0f * nmean[5];
    const float s6 = -2.0f * nstd[6], m6 = -2.0f * nmean[6];
    const float s7 = -2.0f * nstd[7], m7 = -2.0f * nmean[7];
    const float s8 = -2.0f * nstd[8], m8 = -2.0f * nmean[8];
    const float std0 = nstd[0], mean0 = nmean[0];
    const float std1 = nstd[1], mean1 = nmean[1];

    // ---- Stage columns into LDS: t = fmaf(raw, -2s, -2m); cs = 0.25*dot(t,t)
    //      (exact chain from rounds 3-8).
    for (int m = tid; m < NP; m += TPB) {
        const float* p = colsrc + (size_t)m * FD;
        float t0 = fmaf(p[5], s5, m5);
        float t1 = fmaf(p[6], s6, m6);
        float t2 = fmaf(p[7], s7, m7);
        float t3 = fmaf(p[8], s8, m8);
        cvis[m] = make_float4(t0, t1, t2, t3);
        csh[m]  = 0.25f * (t0 * t0 + t1 * t1 + t2 * t2 + t3 * t3);
    }

    // ---- Rows in registers via the proven -0.5*t route (bit-exact lineage).
    float4 rv[RPT];
    float  rthr[RPT];
    float  bestd[RPT];
    int    bblk[RPT];
#pragma unroll
    for (int r = 0; r < RPT; ++r) {
        int n = tid + TPB * r;
        const float* p = rowsrc + (size_t)n * FD;
        float t0 = fmaf(p[5], s5, m5);
        float t1 = fmaf(p[6], s6, m6);
        float t2 = fmaf(p[7], s7, m7);
        float t3 = fmaf(p[8], s8, m8);
        rv[r] = make_float4(-0.5f * t0, -0.5f * t1, -0.5f * t2, -0.5f * t3);
        float rss = 0.25f * (t0 * t0 + t1 * t1 + t2 * t2 + t3 * t3);
        rthr[r] = 6.0f - rss;            // (rs + bestd') > 6  <=>  bestd' > 6 - rs
        bestd[r] = 3.0e38f;
        bblk[r]  = 0;
    }
    __syncthreads();

    // Column-batch load (10 wave-uniform b128) and the R8 compute chain.
    auto loadcols = [&](int g, float4* c, float4& csA, float4& csB) {
        const int m = (g & (NP / 8 - 1)) * 8;
#pragma unroll
        for (int j = 0; j < 8; ++j) c[j] = cvis[m + j];
        csA = *(const float4*)(csh + m);
        csB = *(const float4*)(csh + m + 4);
    };
    auto compute = [&](int m, const float4* c, float4 csA, float4 csB) {
#pragma unroll
        for (int r = 0; r < RPT; ++r) {
            float4 v = rv[r];
            float d0 = fmaf(v.x, c[0].x, csA.x); d0 = fmaf(v.y, c[0].y, d0); d0 = fmaf(v.z, c[0].z, d0); d0 = fmaf(v.w, c[0].w, d0);
            float d1 = fmaf(v.x, c[1].x, csA.y); d1 = fmaf(v.y, c[1].y, d1); d1 = fmaf(v.z, c[1].z, d1); d1 = fmaf(v.w, c[1].w, d1);
            float d2 = fmaf(v.x, c[2].x, csA.z); d2 = fmaf(v.y, c[2].y, d2); d2 = fmaf(v.z, c[2].z, d2); d2 = fmaf(v.w, c[2].w, d2);
            float d3 = fmaf(v.x, c[3].x, csA.w); d3 = fmaf(v.y, c[3].y, d3); d3 = fmaf(v.z, c[3].z, d3); d3 = fmaf(v.w, c[3].w, d3);
            float d4 = fmaf(v.x, c[4].x, csB.x); d4 = fmaf(v.y, c[4].y, d4); d4 = fmaf(v.z, c[4].z, d4); d4 = fmaf(v.w, c[4].w, d4);
            float d5 = fmaf(v.x, c[5].x, csB.y); d5 = fmaf(v.y, c[5].y, d5); d5 = fmaf(v.z, c[5].z, d5); d5 = fmaf(v.w, c[5].w, d5);
            float d6 = fmaf(v.x, c[6].x, csB.z); d6 = fmaf(v.y, c[6].y, d6); d6 = fmaf(v.z, c[6].z, d6); d6 = fmaf(v.w, c[6].w, d6);
            float d7 = fmaf(v.x, c[7].x, csB.w); d7 = fmaf(v.y, c[7].y, d7); d7 = fmaf(v.z, c[7].z, d7); d7 = fmaf(v.w, c[7].w, d7);
            float p0 = fminf(fminf(d0, d1), d2);
            float p1 = fminf(fminf(d3, d4), d5);
            float p2 = fminf(d6, d7);
            float bm = fminf(fminf(p0, p1), p2);
            bool lt = bm < bestd[r];       // strict < keeps FIRST block on ties
            bestd[r] = fminf(bestd[r], bm);
            bblk[r]  = lt ? m : bblk[r];
        }
    };

    // ---- Main loop, register double-buffered (ping-pong A/B).
    float4 ca[8], caA, caB;
    float4 cb[8], cbA, cbB;
    loadcols(0, ca, caA, caB);
    for (int g = 0; g < NP / 8; g += 2) {
        loadcols(g + 1, cb, cbA, cbB);
        compute(g * 8, ca, caA, caB);
        loadcols(g + 2, ca, caA, caB);     // wraps harmlessly at g=126
        compute(g * 8 + 8, cb, cbA, cbB);
    }

    // ---- Epilogue: replay winning block from GLOBAL (staging-chain recompute
    // is bit-identical to LDS contents), recover first-tie index, gather xy.
    float sum = 0.0f;
#pragma unroll
    for (int r = 0; r < RPT; ++r) {
        int n  = tid + TPB * r;
        int mb = bblk[r];
        float4 v = rv[r];
        float dd[8];
#pragma unroll
        for (int j = 0; j < 8; ++j) {
            const float* p = colsrc + (size_t)(mb + j) * FD;
            float t0 = fmaf(p[5], s5, m5);
            float t1 = fmaf(p[6], s6, m6);
            float t2 = fmaf(p[7], s7, m7);
            float t3 = fmaf(p[8], s8, m8);
            float cs = 0.25f * (t0 * t0 + t1 * t1 + t2 * t2 + t3 * t3);
            float t = fmaf(v.x, t0, cs);
            t = fmaf(v.y, t1, t);
            t = fmaf(v.z, t2, t);
            t = fmaf(v.w, t3, t);
            dd[j] = t;
        }
        int sel = 0;
#pragma unroll
        for (int j = 7; j >= 0; --j)       // descending: smallest j wins ties
            if (dd[j] == bestd[r]) sel = j;
        int idx = mb + sel;

        const float* pc = colsrc + (size_t)idx * FD;
        float gx = fmaf(pc[0], std0, mean0);
        float gy = fmaf(pc[1], std1, mean1);
        const float* pr = rowsrc + (size_t)n * FD;
        float ax = fmaf(pr[0], std0, mean0);
        float ay = fmaf(pr[1], std1, mean1);
        float dx = ax - gx;
        float dy = ay - gy;
        float dist = sqrtf(dx * dx + dy * dy);
        if (bestd[r] > rthr[r]) dist = 1.0f;   // min_d > LATENT_DIST_THRESHOLD
        sum += dist;
    }

    // ---- Single-wave reduce, one atomic per block.
    for (int o = 32; o > 0; o >>= 1) sum += __shfl_down(sum, o, 64);
    if (tid == 0) {
        // out[b] = -(sum over 4 views x 2 dirs x 1024 rows) / 8192
        atomicAdd(&out[bid >> 3], sum * (-1.0f / 8192.0f));
    }
}

extern "C" void kernel_launch(void* const* d_in, const int* in_sizes, int n_in,
                              void* d_out, int out_size, void* d_ws, size_t ws_size,
                              hipStream_t stream)
{
    const float* ag = (const float*)d_in[0];   // achieved_goal (128,4,1024,10)
    const float* dg = (const float*)d_in[1];   // desired_goal  (128,4,1024,10)
    const float* nm = (const float*)d_in[2];   // norm_mean (10,)
    const float* ns = (const float*)d_in[3];   // norm_std  (10,)

    hipMemsetAsync(d_out, 0, BSZ * sizeof(float), stream);   // out is accumulated
    chamfer_pairs<<<BSZ * 4 * 2, TPB, 0, stream>>>(ag, dg, nm, ns, (float*)d_out);
}

// Round 10
// 216.453 us; speedup vs baseline: 1.2460x; 1.2460x over previous
//
#include <hip/hip_runtime.h>
#include <cstdint>
#include <cstddef>

#define NP   1024
#define HALF 512
#define FD   10
#define BSZ  128
#define TPB1 128
#define RPT1 8     // rows per lane in scan: 128 threads x 8 = 1024 rows
#define TPB2 256
#define RPT2 4

// d_ws layout (16 MB):
//   wsD : [2048][NP] float  (best shifted distance per row)  @ 0       (8 MB)
//   wsI : [2048][NP] int    (exact argmin column index)      @ 8388608 (8 MB)
#define OFF_I 8388608

// Scan kernel: one block per (pair, dir, col-half). bid = (pair*2 + d)*2 + half.
//   d=0: rows = state(ag), cols = goal(dg)   (reward_s2g)
//   d=1: rows = goal(dg),  cols = state(ag)  (reward_g2s)
// Shift-reduced distance: argmin_m [rs + cs_m - 2 r.c_m] == argmin_m [cs_m + r.c2_m],
// c2 = -2*c staged in LDS (512 cols = 10.25 KB). Tracker keeps the winning
// 8-col block; the exact first-tie index is recovered by replaying the
// identical fmaf chain ON THE SAME LDS VALUES (structurally bit-exact — no
// cross-context recompute, which is what broke rounds 7/9 via fp-contract).
extern "C" __global__ __launch_bounds__(TPB1, 2)
void chamfer_scan(const float* __restrict__ ag, const float* __restrict__ dg,
                  const float* __restrict__ nmean, const float* __restrict__ nstd,
                  float* __restrict__ wsD, int* __restrict__ wsI)
{
    __shared__ __align__(16) float4 cvis[HALF];   // -2 * normalized col vis (8 KB)
    __shared__ __align__(16) float  csh[HALF];    // ||col vis||^2           (2 KB)

    const int bid  = blockIdx.x;        // 0..2047
    const int half = bid & 1;
    const int pd   = bid >> 1;          // pair*2 + d
    const int pair = pd >> 1;
    const int d    = pd & 1;
    const int tid  = threadIdx.x;
    const int cbase = half * HALF;

    const float* rowsrc = ((d == 0) ? ag : dg) + (size_t)pair * (NP * FD);
    const float* colsrc = ((d == 0) ? dg : ag) + (size_t)pair * (NP * FD);

    // -2*(std, mean) for vis features 5..8 (uniform -> scalar regs).
    const float s5 = -2.0f * nstd[5], m5 = -2.0f * nmean[5];
    const float s6 = -2.0f * nstd[6], m6 = -2.0f * nmean[6];
    const float s7 = -2.0f * nstd[7], m7 = -2.0f * nmean[7];
    const float s8 = -2.0f * nstd[8], m8 = -2.0f * nmean[8];

    // ---- Stage this col-half into LDS: t = fmaf(raw, -2s, -2m); cs = 0.25*dot.
    for (int m = tid; m < HALF; m += TPB1) {
        const float* p = colsrc + (size_t)(cbase + m) * FD;
        float t0 = fmaf(p[5], s5, m5);
        float t1 = fmaf(p[6], s6, m6);
        float t2 = fmaf(p[7], s7, m7);
        float t3 = fmaf(p[8], s8, m8);
        cvis[m] = make_float4(t0, t1, t2, t3);
        csh[m]  = 0.25f * (t0 * t0 + t1 * t1 + t2 * t2 + t3 * t3);
    }

    // ---- Rows in registers via the proven -0.5*t route.
    float4 rv[RPT1];
    float  bestd[RPT1];
    int    bblk[RPT1];
#pragma unroll
    for (int r = 0; r < RPT1; ++r) {
        int n = tid + TPB1 * r;
        const float* p = rowsrc + (size_t)n * FD;
        float t0 = fmaf(p[5], s5, m5);
        float t1 = fmaf(p[6], s6, m6);
        float t2 = fmaf(p[7], s7, m7);
        float t3 = fmaf(p[8], s8, m8);
        rv[r] = make_float4(-0.5f * t0, -0.5f * t1, -0.5f * t2, -0.5f * t3);
        bestd[r] = 3.0e38f;
        bblk[r]  = 0;
    }
    __syncthreads();

    // ---- Main loop: 8 cols/iter, 10 wave-uniform b128 broadcasts, R8 chain.
    for (int g = 0; g < HALF / 8; ++g) {
        const int m = g * 8;
        float4 c0 = cvis[m + 0];
        float4 c1 = cvis[m + 1];
        float4 c2 = cvis[m + 2];
        float4 c3 = cvis[m + 3];
        float4 c4 = cvis[m + 4];
        float4 c5 = cvis[m + 5];
        float4 c6 = cvis[m + 6];
        float4 c7 = cvis[m + 7];
        float4 csA = *(const float4*)(csh + m);
        float4 csB = *(const float4*)(csh + m + 4);
#pragma unroll
        for (int r = 0; r < RPT1; ++r) {
            float4 v = rv[r];
            float d0 = fmaf(v.x, c0.x, csA.x); d0 = fmaf(v.y, c0.y, d0); d0 = fmaf(v.z, c0.z, d0); d0 = fmaf(v.w, c0.w, d0);
            float d1 = fmaf(v.x, c1.x, csA.y); d1 = fmaf(v.y, c1.y, d1); d1 = fmaf(v.z, c1.z, d1); d1 = fmaf(v.w, c1.w, d1);
            float d2 = fmaf(v.x, c2.x, csA.z); d2 = fmaf(v.y, c2.y, d2); d2 = fmaf(v.z, c2.z, d2); d2 = fmaf(v.w, c2.w, d2);
            float d3 = fmaf(v.x, c3.x, csA.w); d3 = fmaf(v.y, c3.y, d3); d3 = fmaf(v.z, c3.z, d3); d3 = fmaf(v.w, c3.w, d3);
            float d4 = fmaf(v.x, c4.x, csB.x); d4 = fmaf(v.y, c4.y, d4); d4 = fmaf(v.z, c4.z, d4); d4 = fmaf(v.w, c4.w, d4);
            float d5 = fmaf(v.x, c5.x, csB.y); d5 = fmaf(v.y, c5.y, d5); d5 = fmaf(v.z, c5.z, d5); d5 = fmaf(v.w, c5.w, d5);
            float d6 = fmaf(v.x, c6.x, csB.z); d6 = fmaf(v.y, c6.y, d6); d6 = fmaf(v.z, c6.z, d6); d6 = fmaf(v.w, c6.w, d6);
            float d7 = fmaf(v.x, c7.x, csB.w); d7 = fmaf(v.y, c7.y, d7); d7 = fmaf(v.z, c7.z, d7); d7 = fmaf(v.w, c7.w, d7);
            float p0 = fminf(fminf(d0, d1), d2);
            float p1 = fminf(fminf(d3, d4), d5);
            float p2 = fminf(d6, d7);
            float bm = fminf(fminf(p0, p1), p2);
            bool lt = bm < bestd[r];       // strict < keeps FIRST block on ties
            bestd[r] = fminf(bestd[r], bm);
            bblk[r]  = lt ? m : bblk[r];
        }
    }

    // ---- Replay winning block FROM LDS (same bits the main loop consumed,
    // explicit fmaf chain -> guaranteed bit-exact match), emit (bestd, idx).
#pragma unroll
    for (int r = 0; r < RPT1; ++r) {
        int n  = tid + TPB1 * r;
        int mb = bblk[r];
        float4 v = rv[r];
        float dd[8];
#pragma unroll
        for (int j = 0; j < 8; ++j) {
            float4 c = cvis[mb + j];
            float cs = csh[mb + j];
            float t = fmaf(v.x, c.x, cs);
            t = fmaf(v.y, c.y, t);
            t = fmaf(v.z, c.z, t);
            t = fmaf(v.w, c.w, t);
            dd[j] = t;
        }
        int sel = 0;
#pragma unroll
        for (int j = 7; j >= 0; --j)       // descending: smallest j wins ties
            if (dd[j] == bestd[r]) sel = j;
        wsD[(size_t)bid * NP + n] = bestd[r];
        wsI[(size_t)bid * NP + n] = cbase + mb + sel;   // absolute col index
    }
}

// Merge kernel: one block per (pair, dir). Cross-half min (strict < -> half 0,
// i.e. lower index, wins ties = first occurrence), threshold, xy gather, reduce.
extern "C" __global__ __launch_bounds__(TPB2)
void chamfer_merge(const float* __restrict__ ag, const float* __restrict__ dg,
                   const float* __restrict__ nmean, const float* __restrict__ nstd,
                   const float* __restrict__ wsD, const int* __restrict__ wsI,
                   float* __restrict__ out /* [BSZ], pre-zeroed */)
{
    __shared__ float red[TPB2 / 64];
    const int pd   = blockIdx.x;        // 0..1023
    const int pair = pd >> 1;
    const int d    = pd & 1;
    const int tid  = threadIdx.x;

    const float* rowsrc = ((d == 0) ? ag : dg) + (size_t)pair * (NP * FD);
    const float* colsrc = ((d == 0) ? dg : ag) + (size_t)pair * (NP * FD);

    const float s5 = -2.0f * nstd[5], m5 = -2.0f * nmean[5];
    const float s6 = -2.0f * nstd[6], m6 = -2.0f * nmean[6];
    const float s7 = -2.0f * nstd[7], m7 = -2.0f * nmean[7];
    const float s8 = -2.0f * nstd[8], m8 = -2.0f * nmean[8];
    const float std0 = nstd[0], mean0 = nmean[0];
    const float std1 = nstd[1], mean1 = nmean[1];

    const float* D0 = wsD + (size_t)(pd * 2 + 0) * NP;
    const float* D1 = wsD + (size_t)(pd * 2 + 1) * NP;
    const int*   I0 = wsI + (size_t)(pd * 2 + 0) * NP;
    const int*   I1 = wsI + (size_t)(pd * 2 + 1) * NP;

    float sum = 0.0f;
#pragma unroll
    for (int r = 0; r < RPT2; ++r) {
        int n = tid + TPB2 * r;
        float d0 = D0[n], d1 = D1[n];
        int   i0 = I0[n], i1 = I1[n];
        bool h1 = d1 < d0;                 // strict: ties -> half 0 (lower index)
        float bd = h1 ? d1 : d0;
        int   bi = h1 ? i1 : i0;

        const float* p = rowsrc + (size_t)n * FD;
        float t0 = fmaf(p[5], s5, m5);
        float t1 = fmaf(p[6], s6, m6);
        float t2 = fmaf(p[7], s7, m7);
        float t3 = fmaf(p[8], s8, m8);
        float rss = 0.25f * (t0 * t0 + t1 * t1 + t2 * t2 + t3 * t3);

        const float* pc = colsrc + (size_t)bi * FD;
        float gx = fmaf(pc[0], std0, mean0);
        float gy = fmaf(pc[1], std1, mean1);
        float ax = fmaf(p[0], std0, mean0);
        float ay = fmaf(p[1], std1, mean1);
        float dx = ax - gx;
        float dy = ay - gy;
        float dist = sqrtf(dx * dx + dy * dy);
        if (bd > 6.0f - rss) dist = 1.0f;  // min_d > LATENT_DIST_THRESHOLD
        sum += dist;
    }

    for (int o = 32; o > 0; o >>= 1) sum += __shfl_down(sum, o, 64);
    if ((tid & 63) == 0) red[tid >> 6] = sum;
    __syncthreads();
    if (tid == 0) {
        float s = 0.0f;
#pragma unroll
        for (int w = 0; w < TPB2 / 64; ++w) s += red[w];
        // out[b] = -(sum over 4 views x 2 dirs x 1024 rows) / 8192
        atomicAdd(&out[pd >> 3], s * (-1.0f / 8192.0f));
    }
}

extern "C" void kernel_launch(void* const* d_in, const int* in_sizes, int n_in,
                              void* d_out, int out_size, void* d_ws, size_t ws_size,
                              hipStream_t stream)
{
    const float* ag = (const float*)d_in[0];   // achieved_goal (128,4,1024,10)
    const float* dg = (const float*)d_in[1];   // desired_goal  (128,4,1024,10)
    const float* nm = (const float*)d_in[2];   // norm_mean (10,)
    const float* ns = (const float*)d_in[3];   // norm_std  (10,)

    char*  ws  = (char*)d_ws;
    float* wsD = (float*)ws;                   // 8 MB
    int*   wsI = (int*)(ws + OFF_I);           // 8 MB

    hipMemsetAsync(d_out, 0, BSZ * sizeof(float), stream);   // out is accumulated
    chamfer_scan<<<2048, TPB1, 0, stream>>>(ag, dg, nm, ns, wsD, wsI);
    chamfer_merge<<<1024, TPB2, 0, stream>>>(ag, dg, nm, ns, wsD, wsI, (float*)d_out);
}

// Round 11
// 212.894 us; speedup vs baseline: 1.2668x; 1.0167x over previous
//
#include <hip/hip_runtime.h>
#include <cstdint>
#include <cstddef>

#define NP   1024
#define HALF 512
#define FD   10
#define BSZ  128
#define TPB  256
#define RPT  8    // rows per lane in scan: 64 lanes x 8 = 512 rows (one row-half)

// Register barrier: after this, the compiler cannot prove the value still
// equals the LDS contents, so it must keep it in VGPRs (no LDS re-reads).
#define PIN(f4) asm volatile("" : "+v"(f4.x), "+v"(f4.y), "+v"(f4.z), "+v"(f4.w))

// One block per (pair, dir): bid = pair*2 + d.
//   d=0: rows = state(ag), cols = goal(dg)   (reward_s2g)
//   d=1: rows = goal(dg),  cols = state(ag)  (reward_g2s)
// 4 waves = 2 row-halves x 2 col-halves. Shift-reduced distance:
//   argmin_m [rs + cs_m - 2 r.c_m] == argmin_m [cs_m + r.c2_m],  c2 = -2*c (LDS).
// Each wave scans 512 rows x 512 cols (8-col blocks, min3 tree, block tracker);
// the exact first-tie index is recovered by replaying the identical fmaf chain
// ON THE SAME LDS VALUES (bit-exact — the R7/R9 fp-contract trap is avoided).
// Halves meet in LDS; strict < keeps col-half 0 (lower index) on ties.
extern "C" __global__ __launch_bounds__(TPB, 4)
void chamfer_pairs(const float* __restrict__ ag, const float* __restrict__ dg,
                   const float* __restrict__ nmean, const float* __restrict__ nstd,
                   float* __restrict__ out /* [BSZ], pre-zeroed */)
{
    __shared__ __align__(16) float4 cvis[NP];      // -2*normalized col vis (16 KB)
    __shared__ __align__(16) float  csh[NP];       // ||col vis||^2          (4 KB)
    __shared__ float bD[2 * NP];                   // per (colhalf,row) best  (8 KB)
    __shared__ int   bI[2 * NP];                   // per (colhalf,row) index (8 KB)
    __shared__ float red[TPB / 64];

    const int bid  = blockIdx.x;        // 0..1023: pair*2 + d
    const int pair = bid >> 1;
    const int d    = bid & 1;
    const int tid  = threadIdx.x;
    const int w    = tid >> 6;          // wave 0..3
    const int lane = tid & 63;
    const int rowhalf = w & 1;
    const int colhalf = w >> 1;
    const int cbase   = colhalf * HALF;

    const float* rowsrc = ((d == 0) ? ag : dg) + (size_t)pair * (NP * FD);
    const float* colsrc = ((d == 0) ? dg : ag) + (size_t)pair * (NP * FD);

    // -2*(std, mean) for vis features 5..8 (uniform -> scalar regs).
    const float s5 = -2.0f * nstd[5], m5 = -2.0f * nmean[5];
    const float s6 = -2.0f * nstd[6], m6 = -2.0f * nmean[6];
    const float s7 = -2.0f * nstd[7], m7 = -2.0f * nmean[7];
    const float s8 = -2.0f * nstd[8], m8 = -2.0f * nmean[8];
    const float std0 = nstd[0], mean0 = nmean[0];
    const float std1 = nstd[1], mean1 = nmean[1];

    // ---- Stage ALL columns into LDS: t = fmaf(raw,-2s,-2m); cs = 0.25*dot.
    for (int m = tid; m < NP; m += TPB) {
        const float* p = colsrc + (size_t)m * FD;
        float t0 = fmaf(p[5], s5, m5);
        float t1 = fmaf(p[6], s6, m6);
        float t2 = fmaf(p[7], s7, m7);
        float t3 = fmaf(p[8], s8, m8);
        cvis[m] = make_float4(t0, t1, t2, t3);
        csh[m]  = 0.25f * (t0 * t0 + t1 * t1 + t2 * t2 + t3 * t3);
    }

    // ---- Rows in registers via the proven -0.5*t route.
    float4 rv[RPT];
    float  bestd[RPT];
    int    bblk[RPT];   // ABSOLUTE column index of winning 8-block
#pragma unroll
    for (int r = 0; r < RPT; ++r) {
        int n = rowhalf * HALF + lane + 64 * r;
        const float* p = rowsrc + (size_t)n * FD;
        float t0 = fmaf(p[5], s5, m5);
        float t1 = fmaf(p[6], s6, m6);
        float t2 = fmaf(p[7], s7, m7);
        float t3 = fmaf(p[8], s8, m8);
        rv[r] = make_float4(-0.5f * t0, -0.5f * t1, -0.5f * t2, -0.5f * t3);
        bestd[r] = 3.0e38f;
        bblk[r]  = cbase;
    }
    __syncthreads();

    // ---- Scan this wave's col-half: 8 cols/iter, 10 uniform b128 broadcasts,
    //      batch PINNED in VGPRs so the r-loop never re-touches LDS.
    for (int g = 0; g < HALF / 8; ++g) {
        const int m = cbase + g * 8;
        float4 c0 = cvis[m + 0];
        float4 c1 = cvis[m + 1];
        float4 c2 = cvis[m + 2];
        float4 c3 = cvis[m + 3];
        float4 c4 = cvis[m + 4];
        float4 c5 = cvis[m + 5];
        float4 c6 = cvis[m + 6];
        float4 c7 = cvis[m + 7];
        float4 csA = *(const float4*)(csh + m);
        float4 csB = *(const float4*)(csh + m + 4);
        PIN(c0); PIN(c1); PIN(c2); PIN(c3);
        PIN(c4); PIN(c5); PIN(c6); PIN(c7);
        PIN(csA); PIN(csB);
#pragma unroll
        for (int r = 0; r < RPT; ++r) {
            float4 v = rv[r];
            float d0 = fmaf(v.x, c0.x, csA.x); d0 = fmaf(v.y, c0.y, d0); d0 = fmaf(v.z, c0.z, d0); d0 = fmaf(v.w, c0.w, d0);
            float d1 = fmaf(v.x, c1.x, csA.y); d1 = fmaf(v.y, c1.y, d1); d1 = fmaf(v.z, c1.z, d1); d1 = fmaf(v.w, c1.w, d1);
            float d2 = fmaf(v.x, c2.x, csA.z); d2 = fmaf(v.y, c2.y, d2); d2 = fmaf(v.z, c2.z, d2); d2 = fmaf(v.w, c2.w, d2);
            float d3 = fmaf(v.x, c3.x, csA.w); d3 = fmaf(v.y, c3.y, d3); d3 = fmaf(v.z, c3.z, d3); d3 = fmaf(v.w, c3.w, d3);
            float d4 = fmaf(v.x, c4.x, csB.x); d4 = fmaf(v.y, c4.y, d4); d4 = fmaf(v.z, c4.z, d4); d4 = fmaf(v.w, c4.w, d4);
            float d5 = fmaf(v.x, c5.x, csB.y); d5 = fmaf(v.y, c5.y, d5); d5 = fmaf(v.z, c5.z, d5); d5 = fmaf(v.w, c5.w, d5);
            float d6 = fmaf(v.x, c6.x, csB.z); d6 = fmaf(v.y, c6.y, d6); d6 = fmaf(v.z, c6.z, d6); d6 = fmaf(v.w, c6.w, d6);
            float d7 = fmaf(v.x, c7.x, csB.w); d7 = fmaf(v.y, c7.y, d7); d7 = fmaf(v.z, c7.z, d7); d7 = fmaf(v.w, c7.w, d7);
            float p0 = fminf(fminf(d0, d1), d2);
            float p1 = fminf(fminf(d3, d4), d5);
            float p2 = fminf(d6, d7);
            float bm = fminf(fminf(p0, p1), p2);
            bool lt = bm < bestd[r];       // strict < keeps FIRST block on ties
            bestd[r] = fminf(bestd[r], bm);
            bblk[r]  = lt ? m : bblk[r];
        }
    }

    // ---- Replay winning block FROM LDS (same bits, explicit fmaf chain ->
    //      bit-exact), emit (bestd, idx) into the in-block merge buffers.
#pragma unroll
    for (int r = 0; r < RPT; ++r) {
        int n  = rowhalf * HALF + lane + 64 * r;
        int mb = bblk[r];
        float4 v = rv[r];
        float dd[8];
#pragma unroll
        for (int j = 0; j < 8; ++j) {
            float4 c = cvis[mb + j];
            float cs = csh[mb + j];
            float t = fmaf(v.x, c.x, cs);
            t = fmaf(v.y, c.y, t);
            t = fmaf(v.z, c.z, t);
            t = fmaf(v.w, c.w, t);
            dd[j] = t;
        }
        int sel = 0;
#pragma unroll
        for (int j = 7; j >= 0; --j)       // descending: smallest j wins ties
            if (dd[j] == bestd[r]) sel = j;
        bD[colhalf * NP + n] = bestd[r];
        bI[colhalf * NP + n] = mb + sel;
    }
    __syncthreads();

    // ---- In-block merge: all 4 waves, 4 rows/lane. Strict < -> col-half 0
    //      (lower index) wins ties = first occurrence over the full 1024 cols.
    float sum = 0.0f;
#pragma unroll
    for (int r = 0; r < 4; ++r) {
        int n = tid + TPB * r;
        float d0v = bD[n], d1v = bD[NP + n];
        int   i0 = bI[n], i1 = bI[NP + n];
        bool h1 = d1v < d0v;
        float bd = h1 ? d1v : d0v;
        int   bi = h1 ? i1 : i0;

        const float* p = rowsrc + (size_t)n * FD;
        float t0 = fmaf(p[5], s5, m5);
        float t1 = fmaf(p[6], s6, m6);
        float t2 = fmaf(p[7], s7, m7);
        float t3 = fmaf(p[8], s8, m8);
        float rss = 0.25f * (t0 * t0 + t1 * t1 + t2 * t2 + t3 * t3);

        const float* pc = colsrc + (size_t)bi * FD;
        float gx = fmaf(pc[0], std0, mean0);
        float gy = fmaf(pc[1], std1, mean1);
        float ax = fmaf(p[0], std0, mean0);
        float ay = fmaf(p[1], std1, mean1);
        float dx = ax - gx;
        float dy = ay - gy;
        float dist = sqrtf(dx * dx + dy * dy);
        if (bd > 6.0f - rss) dist = 1.0f;  // min_d > LATENT_DIST_THRESHOLD
        sum += dist;
    }

    // ---- Reduce: wave shuffle, cross-wave LDS, one atomic per block.
    for (int o = 32; o > 0; o >>= 1) sum += __shfl_down(sum, o, 64);
    if (lane == 0) red[w] = sum;
    __syncthreads();
    if (tid == 0) {
        float s = red[0] + red[1] + red[2] + red[3];
        // out[b] = -(sum over 4 views x 2 dirs x 1024 rows) / 8192
        atomicAdd(&out[bid >> 3], s * (-1.0f / 8192.0f));
    }
}

extern "C" void kernel_launch(void* const* d_in, const int* in_sizes, int n_in,
                              void* d_out, int out_size, void* d_ws, size_t ws_size,
                              hipStream_t stream)
{
    const float* ag = (const float*)d_in[0];   // achieved_goal (128,4,1024,10)
    const float* dg = (const float*)d_in[1];   // desired_goal  (128,4,1024,10)
    const float* nm = (const float*)d_in[2];   // norm_mean (10,)
    const float* ns = (const float*)d_in[3];   // norm_std  (10,)

    hipMemsetAsync(d_out, 0, BSZ * sizeof(float), stream);   // out is accumulated
    chamfer_pairs<<<BSZ * 4 * 2, TPB, 0, stream>>>(ag, dg, nm, ns, (float*)d_out);
}

// Round 12
// 210.281 us; speedup vs baseline: 1.2826x; 1.0124x over previous
//
#include <hip/hip_runtime.h>
#include <cstdint>
#include <cstddef>

#define NP   1024
#define HALF 512
#define FD   10
#define BSZ  128
#define TPB  128
#define RPT  16   // rows per lane: 64 lanes x 16 = all 1024 rows per wave

// Register barrier: compiler must keep the value in VGPRs (no LDS re-read,
// no load sinking past this point).
#define PIN(f4) asm volatile("" : "+v"(f4.x), "+v"(f4.y), "+v"(f4.z), "+v"(f4.w))

// Deterministic staging chain — ONLY fmaf/mul ops, so fp-contract has zero
// freedom and any recompute (LDS staging, global replay) is bit-identical.
// t = -2*(raw*std+mean) per vis feature; cs = 0.25*dot(t,t) = ||vis||^2.
__device__ __forceinline__ void stage_one(const float* __restrict__ p,
                                          float s5, float m5, float s6, float m6,
                                          float s7, float m7, float s8, float m8,
                                          float4& t, float& cs)
{
    t.x = fmaf(p[5], s5, m5);
    t.y = fmaf(p[6], s6, m6);
    t.z = fmaf(p[7], s7, m7);
    t.w = fmaf(p[8], s8, m8);
    float a = t.x * t.x;
    a = fmaf(t.y, t.y, a);
    a = fmaf(t.z, t.z, a);
    a = fmaf(t.w, t.w, a);
    cs = 0.25f * a;
}

struct Batch { float4 c[8]; float4 sA, sB; };

// One block per (pair, dir): bid = pair*2 + d.
//   d=0: rows = state(ag), cols = goal(dg)   (reward_s2g)
//   d=1: rows = goal(dg),  cols = state(ag)  (reward_g2s)
// 2 waves per block, one col-half each; every wave scans ALL 1024 rows (RPT=16)
// so each LDS broadcast is amortized over 16 rows. Shift-reduced distance:
//   argmin_m [rs + cs_m - 2 r.c_m] == argmin_m [cs_m + r.c2_m],  c2 = -2*c.
// Main loop: 8 cols/iter, register double-buffered (prefetch next batch, PIN
// anchored). Tracker keeps the winning 8-col block; exact first-tie index is
// recovered by replaying the deterministic chain from GLOBAL (bit-exact by
// construction). Col-halves merge in LDS; strict < keeps half 0 on ties.
extern "C" __global__ __launch_bounds__(TPB, 2)
void chamfer_pairs(const float* __restrict__ ag, const float* __restrict__ dg,
                   const float* __restrict__ nmean, const float* __restrict__ nstd,
                   float* __restrict__ out /* [BSZ], pre-zeroed */)
{
    __shared__ __align__(16) float4 cvis[NP];   // -2*normalized col vis (16 KB)
    __shared__ __align__(16) float  csh[NP];    // ||col vis||^2          (4 KB)
    __shared__ float bD[2 * NP];                // per (colhalf,row) best  (8 KB)
    __shared__ int   bI[2 * NP];                // per (colhalf,row) index (8 KB)
    __shared__ float red[2];

    const int bid  = blockIdx.x;        // 0..1023: pair*2 + d
    const int d    = bid & 1;
    const int pair = bid >> 1;
    const int tid  = threadIdx.x;
    const int w    = tid >> 6;          // wave = col-half (0,1)
    const int lane = tid & 63;
    const int cbase = w * HALF;

    const float* rowsrc = ((d == 0) ? ag : dg) + (size_t)pair * (NP * FD);
    const float* colsrc = ((d == 0) ? dg : ag) + (size_t)pair * (NP * FD);

    const float s5 = -2.0f * nstd[5], m5 = -2.0f * nmean[5];
    const float s6 = -2.0f * nstd[6], m6 = -2.0f * nmean[6];
    const float s7 = -2.0f * nstd[7], m7 = -2.0f * nmean[7];
    const float s8 = -2.0f * nstd[8], m8 = -2.0f * nmean[8];
    const float std0 = nstd[0], mean0 = nmean[0];
    const float std1 = nstd[1], mean1 = nmean[1];

    // ---- Stage ALL columns into LDS via the deterministic chain.
    for (int m = tid; m < NP; m += TPB) {
        float4 t; float cs;
        stage_one(colsrc + (size_t)m * FD, s5, m5, s6, m6, s7, m7, s8, m8, t, cs);
        cvis[m] = t;
        csh[m]  = cs;
    }

    // ---- Rows in registers: rv = -0.5*t (exact), tracker init.
    float4 rv[RPT];
    float  bestd[RPT];
    int    bblk[RPT];
#pragma unroll
    for (int r = 0; r < RPT; ++r) {
        int n = lane + 64 * r;
        float4 t; float cs;
        stage_one(rowsrc + (size_t)n * FD, s5, m5, s6, m6, s7, m7, s8, m8, t, cs);
        rv[r] = make_float4(-0.5f * t.x, -0.5f * t.y, -0.5f * t.z, -0.5f * t.w);
        bestd[r] = 3.0e38f;
        bblk[r]  = cbase;
    }
    __syncthreads();

    // ---- Main loop over this wave's col-half, register double-buffered.
    auto loadb = [&](int g, Batch& b) {
        const int m = cbase + (g & (HALF / 8 - 1)) * 8;
#pragma unroll
        for (int j = 0; j < 8; ++j) b.c[j] = cvis[m + j];
        b.sA = *(const float4*)(csh + m);
        b.sB = *(const float4*)(csh + m + 4);
#pragma unroll
        for (int j = 0; j < 8; ++j) PIN(b.c[j]);
        PIN(b.sA); PIN(b.sB);
    };
    auto computeb = [&](const Batch& b, int g) {
        const int m = cbase + g * 8;
#pragma unroll
        for (int r = 0; r < RPT; ++r) {
            float4 v = rv[r];
            float d0 = fmaf(v.x, b.c[0].x, b.sA.x); d0 = fmaf(v.y, b.c[0].y, d0); d0 = fmaf(v.z, b.c[0].z, d0); d0 = fmaf(v.w, b.c[0].w, d0);
            float d1 = fmaf(v.x, b.c[1].x, b.sA.y); d1 = fmaf(v.y, b.c[1].y, d1); d1 = fmaf(v.z, b.c[1].z, d1); d1 = fmaf(v.w, b.c[1].w, d1);
            float d2 = fmaf(v.x, b.c[2].x, b.sA.z); d2 = fmaf(v.y, b.c[2].y, d2); d2 = fmaf(v.z, b.c[2].z, d2); d2 = fmaf(v.w, b.c[2].w, d2);
            float d3 = fmaf(v.x, b.c[3].x, b.sA.w); d3 = fmaf(v.y, b.c[3].y, d3); d3 = fmaf(v.z, b.c[3].z, d3); d3 = fmaf(v.w, b.c[3].w, d3);
            float d4 = fmaf(v.x, b.c[4].x, b.sB.x); d4 = fmaf(v.y, b.c[4].y, d4); d4 = fmaf(v.z, b.c[4].z, d4); d4 = fmaf(v.w, b.c[4].w, d4);
            float d5 = fmaf(v.x, b.c[5].x, b.sB.y); d5 = fmaf(v.y, b.c[5].y, d5); d5 = fmaf(v.z, b.c[5].z, d5); d5 = fmaf(v.w, b.c[5].w, d5);
            float d6 = fmaf(v.x, b.c[6].x, b.sB.z); d6 = fmaf(v.y, b.c[6].y, d6); d6 = fmaf(v.z, b.c[6].z, d6); d6 = fmaf(v.w, b.c[6].w, d6);
            float d7 = fmaf(v.x, b.c[7].x, b.sB.w); d7 = fmaf(v.y, b.c[7].y, d7); d7 = fmaf(v.z, b.c[7].z, d7); d7 = fmaf(v.w, b.c[7].w, d7);
            float p0 = fminf(fminf(d0, d1), d2);
            float p1 = fminf(fminf(d3, d4), d5);
            float p2 = fminf(d6, d7);
            float bm = fminf(fminf(p0, p1), p2);
            bool lt = bm < bestd[r];       // strict < keeps FIRST block on ties
            bestd[r] = fminf(bestd[r], bm);
            bblk[r]  = lt ? m : bblk[r];
        }
    };

    Batch A, B;
    loadb(0, A);
    for (int g = 0; g < HALF / 8; g += 2) {
        loadb(g + 1, B);
        computeb(A, g);
        loadb(g + 2, A);     // masked wrap at the tail; never consumed
        computeb(B, g + 1);
    }

    // ---- Replay winning block from GLOBAL via the deterministic chain
    //      (bit-identical to the staged values), emit (bestd, idx).
#pragma unroll
    for (int r = 0; r < RPT; ++r) {
        int n  = lane + 64 * r;
        int mb = bblk[r];
        float4 v = rv[r];
        float dd[8];
#pragma unroll
        for (int j = 0; j < 8; ++j) {
            float4 t; float cs;
            stage_one(colsrc + (size_t)(mb + j) * FD, s5, m5, s6, m6, s7, m7, s8, m8, t, cs);
            float u = fmaf(v.x, t.x, cs);
            u = fmaf(v.y, t.y, u);
            u = fmaf(v.z, t.z, u);
            u = fmaf(v.w, t.w, u);
            dd[j] = u;
        }
        int sel = 0;
#pragma unroll
        for (int j = 7; j >= 0; --j)       // descending: smallest j wins ties
            if (dd[j] == bestd[r]) sel = j;
        bD[w * NP + n] = bestd[r];
        bI[w * NP + n] = mb + sel;
    }
    __syncthreads();

    // ---- In-block merge across col-halves: strict < -> half 0 (lower index)
    //      wins ties = first occurrence over the full 1024 columns.
    float sum = 0.0f;
#pragma unroll
    for (int r = 0; r < 8; ++r) {
        int n = tid + TPB * r;
        float d0v = bD[n], d1v = bD[NP + n];
        int   i0 = bI[n], i1 = bI[NP + n];
        bool h1 = d1v < d0v;
        float bd = h1 ? d1v : d0v;
        int   bi = h1 ? i1 : i0;

        const float* p = rowsrc + (size_t)n * FD;
        float4 t; float rss;
        stage_one(p, s5, m5, s6, m6, s7, m7, s8, m8, t, rss);

        const float* pc = colsrc + (size_t)bi * FD;
        float gx = fmaf(pc[0], std0, mean0);
        float gy = fmaf(pc[1], std1, mean1);
        float ax = fmaf(p[0], std0, mean0);
        float ay = fmaf(p[1], std1, mean1);
        float dx = ax - gx;
        float dy = ay - gy;
        float dist = sqrtf(dx * dx + dy * dy);
        if (bd > 6.0f - rss) dist = 1.0f;  // min_d > LATENT_DIST_THRESHOLD
        sum += dist;
    }

    // ---- Reduce: wave shuffle, cross-wave LDS, one atomic per block.
    for (int o = 32; o > 0; o >>= 1) sum += __shfl_down(sum, o, 64);
    if (lane == 0) red[w] = sum;
    __syncthreads();
    if (tid == 0) {
        float s = red[0] + red[1];
        // out[b] = -(sum over 4 views x 2 dirs x 1024 rows) / 8192
        atomicAdd(&out[bid >> 3], s * (-1.0f / 8192.0f));
    }
}

extern "C" void kernel_launch(void* const* d_in, const int* in_sizes, int n_in,
                              void* d_out, int out_size, void* d_ws, size_t ws_size,
                              hipStream_t stream)
{
    const float* ag = (const float*)d_in[0];   // achieved_goal (128,4,1024,10)
    const float* dg = (const float*)d_in[1];   // desired_goal  (128,4,1024,10)
    const float* nm = (const float*)d_in[2];   // norm_mean (10,)
    const float* ns = (const float*)d_in[3];   // norm_std  (10,)

    hipMemsetAsync(d_out, 0, BSZ * sizeof(float), stream);   // out is accumulated
    chamfer_pairs<<<BSZ * 4 * 2, TPB, 0, stream>>>(ag, dg, nm, ns, (float*)d_out);
}

// Round 13
// 208.566 us; speedup vs baseline: 1.2931x; 1.0082x over previous
//
#include <hip/hip_runtime.h>
#include <cstdint>
#include <cstddef>

#define NP   1024
#define HALF 512
#define FD   10
#define BSZ  128
#define TPB  256
#define RPT  8    // rows per lane: 64 lanes x 8 = 512 rows (one row-half) per wave

// Register barrier: compiler must keep the value in VGPRs (no LDS re-read,
// no load sinking past this point).
#define PIN(f4) asm volatile("" : "+v"(f4.x), "+v"(f4.y), "+v"(f4.z), "+v"(f4.w))

// Deterministic staging chain — ONLY fmaf/mul ops, so fp-contract has zero
// freedom and any recompute (LDS staging, global replay) is bit-identical.
// t = -2*(raw*std+mean) per vis feature; cs = 0.25*dot(t,t) = ||vis||^2.
__device__ __forceinline__ void stage_one(const float* __restrict__ p,
                                          float s5, float m5, float s6, float m6,
                                          float s7, float m7, float s8, float m8,
                                          float4& t, float& cs)
{
    t.x = fmaf(p[5], s5, m5);
    t.y = fmaf(p[6], s6, m6);
    t.z = fmaf(p[7], s7, m7);
    t.w = fmaf(p[8], s8, m8);
    float a = t.x * t.x;
    a = fmaf(t.y, t.y, a);
    a = fmaf(t.z, t.z, a);
    a = fmaf(t.w, t.w, a);
    cs = 0.25f * a;
}

// One block per (pair, dir): bid = pair*2 + d.
//   d=0: rows = state(ag), cols = goal(dg)   (reward_s2g)
//   d=1: rows = goal(dg),  cols = state(ag)  (reward_g2s)
// 4 waves = 2 row-halves x 2 col-halves; 36.5 KB LDS -> 4 blocks/CU = 16
// waves/CU = 4 waves/SIMD (the R11-vs-R12 A/B showed waves/SIMD is the
// dominant variable). amdgpu_waves_per_eu(4,4) pins the VGPR budget at 128
// so the allocator cannot crush to the 8-wave tier and evict row registers
// (R11's VGPR=60 failure). Shift-reduced distance:
//   argmin_m [rs + cs_m - 2 r.c_m] == argmin_m [cs_m + r.c2_m],  c2 = -2*c.
// Tracker keeps the winning 8-col block; exact first-tie index is recovered
// by replaying the deterministic chain from GLOBAL (bit-exact by
// construction; keeps the LDS pipe conflict-free). Col-halves merge in LDS;
// strict < keeps half 0 (lower index) on ties = first occurrence.
extern "C" __global__ __launch_bounds__(TPB)
__attribute__((amdgpu_waves_per_eu(4, 4)))
void chamfer_pairs(const float* __restrict__ ag, const float* __restrict__ dg,
                   const float* __restrict__ nmean, const float* __restrict__ nstd,
                   float* __restrict__ out /* [BSZ], pre-zeroed */)
{
    __shared__ __align__(16) float4 cvis[NP];   // -2*normalized col vis (16 KB)
    __shared__ __align__(16) float  csh[NP];    // ||col vis||^2          (4 KB)
    __shared__ float bD[2 * NP];                // per (colhalf,row) best  (8 KB)
    __shared__ int   bI[2 * NP];                // per (colhalf,row) index (8 KB)
    __shared__ float red[4];

    const int bid  = blockIdx.x;        // 0..1023: pair*2 + d
    const int d    = bid & 1;
    const int pair = bid >> 1;
    const int tid  = threadIdx.x;
    const int w    = tid >> 6;          // wave 0..3
    const int lane = tid & 63;
    const int rowhalf = w & 1;
    const int colhalf = w >> 1;
    const int cbase   = colhalf * HALF;

    const float* rowsrc = ((d == 0) ? ag : dg) + (size_t)pair * (NP * FD);
    const float* colsrc = ((d == 0) ? dg : ag) + (size_t)pair * (NP * FD);

    const float s5 = -2.0f * nstd[5], m5 = -2.0f * nmean[5];
    const float s6 = -2.0f * nstd[6], m6 = -2.0f * nmean[6];
    const float s7 = -2.0f * nstd[7], m7 = -2.0f * nmean[7];
    const float s8 = -2.0f * nstd[8], m8 = -2.0f * nmean[8];
    const float std0 = nstd[0], mean0 = nmean[0];
    const float std1 = nstd[1], mean1 = nmean[1];

    // ---- Stage ALL columns into LDS via the deterministic chain.
    for (int m = tid; m < NP; m += TPB) {
        float4 t; float cs;
        stage_one(colsrc + (size_t)m * FD, s5, m5, s6, m6, s7, m7, s8, m8, t, cs);
        cvis[m] = t;
        csh[m]  = cs;
    }

    // ---- Rows in registers: rv = -0.5*t (exact), tracker init.
    float4 rv[RPT];
    float  bestd[RPT];
    int    bblk[RPT];
#pragma unroll
    for (int r = 0; r < RPT; ++r) {
        int n = rowhalf * HALF + lane + 64 * r;
        float4 t; float cs;
        stage_one(rowsrc + (size_t)n * FD, s5, m5, s6, m6, s7, m7, s8, m8, t, cs);
        rv[r] = make_float4(-0.5f * t.x, -0.5f * t.y, -0.5f * t.z, -0.5f * t.w);
        bestd[r] = 3.0e38f;
        bblk[r]  = cbase;
    }
    __syncthreads();

    // ---- Scan this wave's col-half: 8 cols/iter, 10 uniform b128 broadcasts,
    //      batch PINNED in VGPRs; 4 waves/SIMD hide the lgkmcnt waits.
    for (int g = 0; g < HALF / 8; ++g) {
        const int m = cbase + g * 8;
        float4 c0 = cvis[m + 0];
        float4 c1 = cvis[m + 1];
        float4 c2 = cvis[m + 2];
        float4 c3 = cvis[m + 3];
        float4 c4 = cvis[m + 4];
        float4 c5 = cvis[m + 5];
        float4 c6 = cvis[m + 6];
        float4 c7 = cvis[m + 7];
        float4 csA = *(const float4*)(csh + m);
        float4 csB = *(const float4*)(csh + m + 4);
        PIN(c0); PIN(c1); PIN(c2); PIN(c3);
        PIN(c4); PIN(c5); PIN(c6); PIN(c7);
        PIN(csA); PIN(csB);
#pragma unroll
        for (int r = 0; r < RPT; ++r) {
            float4 v = rv[r];
            float d0 = fmaf(v.x, c0.x, csA.x); d0 = fmaf(v.y, c0.y, d0); d0 = fmaf(v.z, c0.z, d0); d0 = fmaf(v.w, c0.w, d0);
            float d1 = fmaf(v.x, c1.x, csA.y); d1 = fmaf(v.y, c1.y, d1); d1 = fmaf(v.z, c1.z, d1); d1 = fmaf(v.w, c1.w, d1);
            float d2 = fmaf(v.x, c2.x, csA.z); d2 = fmaf(v.y, c2.y, d2); d2 = fmaf(v.z, c2.z, d2); d2 = fmaf(v.w, c2.w, d2);
            float d3 = fmaf(v.x, c3.x, csA.w); d3 = fmaf(v.y, c3.y, d3); d3 = fmaf(v.z, c3.z, d3); d3 = fmaf(v.w, c3.w, d3);
            float d4 = fmaf(v.x, c4.x, csB.x); d4 = fmaf(v.y, c4.y, d4); d4 = fmaf(v.z, c4.z, d4); d4 = fmaf(v.w, c4.w, d4);
            float d5 = fmaf(v.x, c5.x, csB.y); d5 = fmaf(v.y, c5.y, d5); d5 = fmaf(v.z, c5.z, d5); d5 = fmaf(v.w, c5.w, d5);
            float d6 = fmaf(v.x, c6.x, csB.z); d6 = fmaf(v.y, c6.y, d6); d6 = fmaf(v.z, c6.z, d6); d6 = fmaf(v.w, c6.w, d6);
            float d7 = fmaf(v.x, c7.x, csB.w); d7 = fmaf(v.y, c7.y, d7); d7 = fmaf(v.z, c7.z, d7); d7 = fmaf(v.w, c7.w, d7);
            float p0 = fminf(fminf(d0, d1), d2);
            float p1 = fminf(fminf(d3, d4), d5);
            float p2 = fminf(d6, d7);
            float bm = fminf(fminf(p0, p1), p2);
            bool lt = bm < bestd[r];       // strict < keeps FIRST block on ties
            bestd[r] = fminf(bestd[r], bm);
            bblk[r]  = lt ? m : bblk[r];
        }
    }

    // ---- Replay winning block from GLOBAL via the deterministic chain
    //      (bit-identical to the staged values), emit (bestd, idx).
#pragma unroll
    for (int r = 0; r < RPT; ++r) {
        int n  = rowhalf * HALF + lane + 64 * r;
        int mb = bblk[r];
        float4 v = rv[r];
        float dd[8];
#pragma unroll
        for (int j = 0; j < 8; ++j) {
            float4 t; float cs;
            stage_one(colsrc + (size_t)(mb + j) * FD, s5, m5, s6, m6, s7, m7, s8, m8, t, cs);
            float u = fmaf(v.x, t.x, cs);
            u = fmaf(v.y, t.y, u);
            u = fmaf(v.z, t.z, u);
            u = fmaf(v.w, t.w, u);
            dd[j] = u;
        }
        int sel = 0;
#pragma unroll
        for (int j = 7; j >= 0; --j)       // descending: smallest j wins ties
            if (dd[j] == bestd[r]) sel = j;
        bD[colhalf * NP + n] = bestd[r];
        bI[colhalf * NP + n] = mb + sel;
    }
    __syncthreads();

    // ---- In-block merge across col-halves: strict < -> half 0 (lower index)
    //      wins ties = first occurrence over the full 1024 columns.
    float sum = 0.0f;
#pragma unroll
    for (int r = 0; r < 4; ++r) {
        int n = tid + TPB * r;
        float d0v = bD[n], d1v = bD[NP + n];
        int   i0 = bI[n], i1 = bI[NP + n];
        bool h1 = d1v < d0v;
        float bd = h1 ? d1v : d0v;
        int   bi = h1 ? i1 : i0;

        const float* p = rowsrc + (size_t)n * FD;
        float4 t; float rss;
        stage_one(p, s5, m5, s6, m6, s7, m7, s8, m8, t, rss);

        const float* pc = colsrc + (size_t)bi * FD;
        float gx = fmaf(pc[0], std0, mean0);
        float gy = fmaf(pc[1], std1, mean1);
        float ax = fmaf(p[0], std0, mean0);
        float ay = fmaf(p[1], std1, mean1);
        float dx = ax - gx;
        float dy = ay - gy;
        float dist = sqrtf(dx * dx + dy * dy);
        if (bd > 6.0f - rss) dist = 1.0f;  // min_d > LATENT_DIST_THRESHOLD
        sum += dist;
    }

    // ---- Reduce: wave shuffle, cross-wave LDS, one atomic per block.
    for (int o = 32; o > 0; o >>= 1) sum += __shfl_down(sum, o, 64);
    if (lane == 0) red[w] = sum;
    __syncthreads();
    if (tid == 0) {
        float s = red[0] + red[1] + red[2] + red[3];
        // out[b] = -(sum over 4 views x 2 dirs x 1024 rows) / 8192
        atomicAdd(&out[bid >> 3], s * (-1.0f / 8192.0f));
    }
}

extern "C" void kernel_launch(void* const* d_in, const int* in_sizes, int n_in,
                              void* d_out, int out_size, void* d_ws, size_t ws_size,
                              hipStream_t stream)
{
    const float* ag = (const float*)d_in[0];   // achieved_goal (128,4,1024,10)
    const float* dg = (const float*)d_in[1];   // desired_goal  (128,4,1024,10)
    const float* nm = (const float*)d_in[2];   // norm_mean (10,)
    const float* ns = (const float*)d_in[3];   // norm_std  (10,)

    hipMemsetAsync(d_out, 0, BSZ * sizeof(float), stream);   // out is accumulated
    chamfer_pairs<<<BSZ * 4 * 2, TPB, 0, stream>>>(ag, dg, nm, ns, (float*)d_out);
}